// Round 9
// baseline (14033.151 us; speedup 1.0000x reference)
//
#include <hip/hip_runtime.h>
#include <hip/hip_bf16.h>
#include <stdint.h>

#define TT 512
#define BB 32
#define II 256
#define HH 512
#define OO 256
#define N4H 2048
#define PADE 2048                      // 4KB pad per (dir,t) block
#define HBLKE (BB * HH + PADE)
#define TTHB ((size_t)TT * HBLKE)

typedef __attribute__((ext_vector_type(8))) short bf16x8;
typedef __attribute__((ext_vector_type(4))) float f32x4;

#define KEEPV(x) asm volatile("" : "+v"(x))

static __device__ __forceinline__ f32x4 MFMA(bf16x8 a, bf16x8 b, f32x4 c) {
  return __builtin_amdgcn_mfma_f32_16x16x32_bf16(a, b, c, 0, 0, 0);
}
static __device__ __forceinline__ unsigned short f2bf(float x) {
  union { float f; unsigned u; } v; v.f = x;
  unsigned r = v.u + 0x7FFFu + ((v.u >> 16) & 1u);
  return (unsigned short)(r >> 16);
}
static __device__ __forceinline__ float bf2f(unsigned short b) {
  union { unsigned u; float f; } v; v.u = ((unsigned)b) << 16; return v.f;
}
static __device__ __forceinline__ float sigm(float x) {
  return 1.0f / (1.0f + __expf(-x));
}
static __device__ __forceinline__ float tanh_(float x) {
  return 1.0f - 2.0f / (1.0f + __expf(2.0f * x));
}

// ---------------- prep kernels ----------------

__global__ void prep_w(const float* __restrict__ src, unsigned short* __restrict__ hi,
                       unsigned short* __restrict__ lo, int K, int N, int packed) {
  int tid = blockIdx.x * 256 + threadIdx.x;
  int nch = K >> 3;
  if (tid >= N * nch) return;
  int c = tid / nch;
  int j = (tid - c * nch) << 3;
  int row = packed ? ((c & 3) * HH + (c >> 2)) : c;
  const float* s = src + (size_t)row * K + j;
  alignas(16) unsigned short h8[8];
  alignas(16) unsigned short l8[8];
#pragma unroll
  for (int e = 0; e < 8; ++e) {
    float v = s[e];
    unsigned short hb = f2bf(v);
    h8[e] = hb;
    l8[e] = f2bf(v - bf2f(hb));
  }
  *(uint4*)(hi + (size_t)c * K + j) = *(const uint4*)h8;
  *(uint4*)(lo + (size_t)c * K + j) = *(const uint4*)l8;
}

__global__ void prep_bias(const float* __restrict__ bi0, const float* __restrict__ bh0,
                          const float* __restrict__ bim, const float* __restrict__ bhm,
                          float* __restrict__ bias0p, float* __restrict__ biasmp) {
  int c = blockIdx.x * 256 + threadIdx.x;
  if (c >= N4H) return;
  int row = (c & 3) * HH + (c >> 2);
  bias0p[c] = bi0[row] + bh0[row];
  biasmp[c] = bim[row] + bhm[row];
}

__global__ void prep_x(const float* __restrict__ in, unsigned short* __restrict__ xb) {
  int tid = blockIdx.x * 256 + threadIdx.x;
  if (tid >= 16384 * 32) return;
  int row = tid >> 5, j = (tid & 31) << 3;
  int t = row >> 5, b = row & 31;
  const float* s = in + ((size_t)b * TT + t) * II + j;
  alignas(16) unsigned short o8[8];
#pragma unroll
  for (int e = 0; e < 8; ++e) o8[e] = f2bf(s[e]);
  *(uint4*)(xb + (size_t)row * II + j) = *(const uint4*)o8;
}

// ---------------- big GEMMs ----------------

__global__ __launch_bounds__(256) void gemm_g0(
    const unsigned short* __restrict__ A, const unsigned short* __restrict__ Bhi,
    const unsigned short* __restrict__ Blo, const float* __restrict__ biasp,
    float* __restrict__ out) {
  const int K = II;
  int wgm = blockIdx.x & 255;
  int wgn = blockIdx.x >> 8;
  int l = threadIdx.x & 63, wave = threadIdx.x >> 6;
  int mbase = wgm * 64 + wave * 16;
  int nbase = wgn * 64;
  int arow = mbase + (l & 15);
  int koff = (l >> 4) * 8;
  f32x4 acc[4] = {};
  for (int kt = 0; kt < K / 32; ++kt) {
    bf16x8 a = *(const bf16x8*)(A + (size_t)arow * K + kt * 32 + koff);
#pragma unroll
    for (int n = 0; n < 4; ++n) {
      int col = nbase + n * 16 + (l & 15);
      bf16x8 bh = *(const bf16x8*)(Bhi + (size_t)col * K + kt * 32 + koff);
      bf16x8 bl = *(const bf16x8*)(Blo + (size_t)col * K + kt * 32 + koff);
      acc[n] = MFMA(a, bh, acc[n]);
      acc[n] = MFMA(a, bl, acc[n]);
    }
  }
#pragma unroll
  for (int n = 0; n < 4; ++n) {
    int col = nbase + n * 16 + (l & 15);
    float bv = biasp[col];
#pragma unroll
    for (int r = 0; r < 4; ++r) {
      int row = mbase + (l >> 4) * 4 + r;
      out[(size_t)row * N4H + col] = acc[n][r] + bv;
    }
  }
}

// g1x[dir][t][b][2048] = h0[dir][t][b][:] @ Wx_mid^T (hi+lo) + biasmp
// rows 0..16383 -> outf (reused g0x buffer), 16384..32767 -> outb
__global__ __launch_bounds__(256) void gemm_g1x(
    const unsigned short* __restrict__ h0, const unsigned short* __restrict__ Bhi,
    const unsigned short* __restrict__ Blo, const float* __restrict__ biasp,
    float* __restrict__ outf, float* __restrict__ outb) {
  int wgm = blockIdx.x & 511;
  int wgn = blockIdx.x >> 9;
  int l = threadIdx.x & 63, wave = threadIdx.x >> 6;
  int mbase = wgm * 64 + wave * 16;          // [0, 32768)
  int nbase = wgn * 64;
  int arow = mbase + (l & 15);
  int dirreg = arow >> 14;
  int rr = arow & 16383;
  const unsigned short* Arow = h0 + (size_t)dirreg * TTHB +
                               (size_t)(rr >> 5) * HBLKE + (size_t)(rr & 31) * HH;
  int koff = (l >> 4) * 8;
  f32x4 acc[4] = {};
  for (int kt = 0; kt < 16; ++kt) {
    bf16x8 a = *(const bf16x8*)(Arow + kt * 32 + koff);
#pragma unroll
    for (int n = 0; n < 4; ++n) {
      int col = nbase + n * 16 + (l & 15);
      bf16x8 bh = *(const bf16x8*)(Bhi + (size_t)col * HH + kt * 32 + koff);
      bf16x8 bl = *(const bf16x8*)(Blo + (size_t)col * HH + kt * 32 + koff);
      acc[n] = MFMA(a, bh, acc[n]);
      acc[n] = MFMA(a, bl, acc[n]);
    }
  }
#pragma unroll
  for (int n = 0; n < 4; ++n) {
    int col = nbase + n * 16 + (l & 15);
    float bv = biasp[col];
#pragma unroll
    for (int r = 0; r < 4; ++r) {
      int row = mbase + (l >> 4) * 4 + r;
      int dr = row >> 14, r2 = row & 16383;
      float* o = (dr ? outb : outf) + (size_t)r2 * N4H + col;
      *o = acc[n][r] + bv;
    }
  }
}

__global__ __launch_bounds__(256) void gemm_fc(
    const unsigned short* __restrict__ A, const unsigned short* __restrict__ Bhi,
    const unsigned short* __restrict__ Blo, const float* __restrict__ bias,
    float* __restrict__ y) {
  const int K = 2 * HH;
  int wgm = blockIdx.x & 255;
  int wgn = blockIdx.x >> 8;
  int l = threadIdx.x & 63, wave = threadIdx.x >> 6;
  int mbase = wgm * 64 + wave * 16;
  int nbase = wgn * 64;
  int arow = mbase + (l & 15);
  int koff = (l >> 4) * 8;
  int t0 = arow >> 5, b0 = arow & 31;
  const unsigned short* Af = A + (size_t)t0 * HBLKE + (size_t)b0 * HH;
  const unsigned short* Ab = Af + TTHB;
  f32x4 acc[4] = {};
#pragma unroll
  for (int kt = 0; kt < K / 32; ++kt) {
    const unsigned short* ap =
        (kt < 16) ? (Af + kt * 32 + koff) : (Ab + (kt - 16) * 32 + koff);
    bf16x8 a = *(const bf16x8*)ap;
#pragma unroll
    for (int n = 0; n < 4; ++n) {
      int col = nbase + n * 16 + (l & 15);
      bf16x8 bh = *(const bf16x8*)(Bhi + (size_t)col * K + kt * 32 + koff);
      bf16x8 bl = *(const bf16x8*)(Blo + (size_t)col * K + kt * 32 + koff);
      acc[n] = MFMA(a, bh, acc[n]);
      acc[n] = MFMA(a, bl, acc[n]);
    }
  }
#pragma unroll
  for (int n = 0; n < 4; ++n) {
    int col = nbase + n * 16 + (l & 15);
    float bv = bias[col];
#pragma unroll
    for (int r = 0; r < 4; ++r) {
      int row = mbase + (l >> 4) * 4 + r;
      int t = row >> 5, b = row & 31;
      y[((size_t)b * TT + t) * OO + col] = acc[n][r] + bv;
    }
  }
}

// ---------------- scans ----------------
// Sync = R7 proven pattern: 16-bit agent atomic h-stores -> __syncthreads ->
// flag; consumer poll + __threadfence + plain loads. 32 frags = 128 VGPRs
// KEEPV-pinned per wave (the config whose pin provably held in R7: VGPR=164).

static __device__ __forceinline__ void wait1(const unsigned* f, unsigned tgt) {
  const int l = threadIdx.x & 63;
  while (true) {
    unsigned v = __hip_atomic_load(f + l, __ATOMIC_RELAXED, __HIP_MEMORY_SCOPE_AGENT);
    if (__all((int)(v >= tgt))) break;
    __builtin_amdgcn_s_sleep(1);
  }
  __threadfence();
}

// 128 WGs: dir = bid>>6, wg = bid&63. g-fed scan over W0 (layer 0).
__global__ void __launch_bounds__(256, 1) scan_l0(
    const unsigned short* __restrict__ Whi, const unsigned short* __restrict__ Wlo,
    const float* __restrict__ g0x, unsigned short* __restrict__ h0,
    unsigned int* __restrict__ flags) {
  const int bid = blockIdx.x;
  const int dir = bid >> 6;
  const int wg = bid & 63;
  const int tid = threadIdx.x;
  const int l = tid & 63;
  const int wave = tid >> 6;
  const int cg = wave & 1;
  const int rg = wave >> 1;
  const int col = wg * 32 + cg * 16 + (l & 15);
  const int gate = col & 3;
  const int ug = col >> 2;
  const int kq = (l >> 4) * 8;
  const int q = l & 60;
  const int arow = rg * 16 + (l & 15);
  const int crow = rg * 16 + (l >> 4) * 4;
  const int srow = crow + (l & 3);
  unsigned int* myf = flags + dir * 64;
  unsigned short* hreg = h0 + (size_t)dir * TTHB;

  bf16x8 wr_h[16], wr_l[16];
  {
    const unsigned short* p1 = Whi + (size_t)col * HH + kq;
    const unsigned short* p2 = Wlo + (size_t)col * HH + kq;
#pragma unroll
    for (int kt = 0; kt < 16; ++kt) {
      wr_h[kt] = *(const bf16x8*)(p1 + kt * 32);
      wr_l[kt] = *(const bf16x8*)(p2 + kt * 32);
    }
#pragma unroll
    for (int kt = 0; kt < 16; ++kt) { KEEPV(wr_h[kt]); KEEPV(wr_l[kt]); }
  }
  float cprev[4] = {0.f, 0.f, 0.f, 0.f};
  for (int t = 0; t < TT; ++t) {
    const int tin = dir ? (TT - 1 - t) : t;
    f32x4 acc;
    const float* gp = g0x + ((size_t)tin * BB + crow) * N4H + col;
#pragma unroll
    for (int r = 0; r < 4; ++r) acc[r] = gp[(size_t)r * N4H];
    if (t > 0) {
      wait1(myf, (unsigned)t);
      const unsigned short* ap =
          hreg + (size_t)(t - 1) * HBLKE + (size_t)arow * HH + kq;
#pragma unroll
      for (int kt = 0; kt < 16; ++kt) {
        bf16x8 a = *(const bf16x8*)(ap + kt * 32);
        acc = MFMA(a, wr_h[kt], acc);
        acc = MFMA(a, wr_l[kt], acc);
      }
    }
    float hsel = 0.f;
#pragma unroll
    for (int r = 0; r < 4; ++r) {
      float pre = acc[r];
      float own = (gate == 2) ? tanh_(pre) : sigm(pre);
      float iv = __shfl(own, q + 0, 64);
      float fv = __shfl(own, q + 1, 64);
      float gv = __shfl(own, q + 2, 64);
      float ov = __shfl(own, q + 3, 64);
      float cn = fv * cprev[r] + iv * gv;
      cprev[r] = cn;
      float hv = ov * tanh_(cn);
      if ((l & 3) == r) hsel = hv;
    }
    __hip_atomic_store(hreg + (size_t)t * HBLKE + (size_t)srow * HH + ug,
                       f2bf(hsel), __ATOMIC_RELAXED, __HIP_MEMORY_SCOPE_AGENT);
    __syncthreads();
    if (tid == 0)
      __hip_atomic_store(myf + wg, (unsigned)(t + 1), __ATOMIC_RELAXED,
                         __HIP_MEMORY_SCOPE_AGENT);
  }
}

// 128 WGs: g1x-fed scan over Wr_mid + external outputs.
__global__ void __launch_bounds__(256, 1) scan_l1(
    const unsigned short* __restrict__ Whi, const unsigned short* __restrict__ Wlo,
    const float* __restrict__ g1xf, const float* __restrict__ g1xb,
    unsigned short* __restrict__ out1, float* __restrict__ gates,
    float* __restrict__ hn, unsigned int* __restrict__ flags) {
  const int bid = blockIdx.x;
  const int dir = bid >> 6;
  const int wg = bid & 63;
  const int tid = threadIdx.x;
  const int l = tid & 63;
  const int wave = tid >> 6;
  const int cg = wave & 1;
  const int rg = wave >> 1;
  const int col = wg * 32 + cg * 16 + (l & 15);
  const int gate = col & 3;
  const int ug = col >> 2;
  const int kq = (l >> 4) * 8;
  const int q = l & 60;
  const int arow = rg * 16 + (l & 15);
  const int crow = rg * 16 + (l >> 4) * 4;
  const int srow = crow + (l & 3);
  unsigned int* myf = flags + dir * 64;
  unsigned short* oreg = out1 + (size_t)dir * TTHB;
  const float* gg = dir ? g1xb : g1xf;

  bf16x8 wr_h[16], wr_l[16];
  {
    const unsigned short* p1 = Whi + (size_t)col * HH + kq;
    const unsigned short* p2 = Wlo + (size_t)col * HH + kq;
#pragma unroll
    for (int kt = 0; kt < 16; ++kt) {
      wr_h[kt] = *(const bf16x8*)(p1 + kt * 32);
      wr_l[kt] = *(const bf16x8*)(p2 + kt * 32);
    }
#pragma unroll
    for (int kt = 0; kt < 16; ++kt) { KEEPV(wr_h[kt]); KEEPV(wr_l[kt]); }
  }
  float cprev[4] = {0.f, 0.f, 0.f, 0.f};
  for (int t = 0; t < TT; ++t) {
    f32x4 acc;
    const float* gp = gg + ((size_t)t * BB + crow) * N4H + col;
#pragma unroll
    for (int r = 0; r < 4; ++r) acc[r] = gp[(size_t)r * N4H];
    if (t > 0) {
      wait1(myf, (unsigned)t);
      const unsigned short* ap =
          oreg + (size_t)(t - 1) * HBLKE + (size_t)arow * HH + kq;
#pragma unroll
      for (int kt = 0; kt < 16; ++kt) {
        bf16x8 a = *(const bf16x8*)(ap + kt * 32);
        acc = MFMA(a, wr_h[kt], acc);
        acc = MFMA(a, wr_l[kt], acc);
      }
    }
    float hsel = 0.f, own4[4], cn4[4];
#pragma unroll
    for (int r = 0; r < 4; ++r) {
      float pre = acc[r];
      float own = (gate == 2) ? tanh_(pre) : sigm(pre);
      own4[r] = own;
      float iv = __shfl(own, q + 0, 64);
      float fv = __shfl(own, q + 1, 64);
      float gv = __shfl(own, q + 2, 64);
      float ov = __shfl(own, q + 3, 64);
      float cn = fv * cprev[r] + iv * gv;
      cprev[r] = cn;
      cn4[r] = cn;
      float hv = ov * tanh_(cn);
      if ((l & 3) == r) hsel = hv;
    }
    __hip_atomic_store(oreg + (size_t)t * HBLKE + (size_t)srow * HH + ug,
                       f2bf(hsel), __ATOMIC_RELAXED, __HIP_MEMORY_SCOPE_AGENT);
    __syncthreads();
    if (tid == 0)
      __hip_atomic_store(myf + wg, (unsigned)(t + 1), __ATOMIC_RELAXED,
                         __HIP_MEMORY_SCOPE_AGENT);
    // external outputs after the release (off the recurrence critical path)
#pragma unroll
    for (int r = 0; r < 4; ++r)
      gates[(((size_t)t * 4 + gate) * BB + crow + r) * (2 * HH) + dir * HH + ug] = own4[r];
    if (gate == 1) {
#pragma unroll
      for (int r = 0; r < 4; ++r)
        hn[((size_t)t * BB + crow + r) * (2 * HH) + dir * HH + ug] = cn4[r];
    }
  }
}

// ---------------- host ----------------
extern "C" void kernel_launch(void* const* d_in, const int* in_sizes, int n_in,
                              void* d_out, int out_size, void* d_ws, size_t ws_size,
                              hipStream_t stream) {
  const float* inputs   = (const float*)d_in[0];
  const float* w_ih_in  = (const float*)d_in[1];
  const float* w_hh_in  = (const float*)d_in[2];
  const float* b_ih_in  = (const float*)d_in[3];
  const float* b_hh_in  = (const float*)d_in[4];
  const float* w_ih_mid = (const float*)d_in[5];
  const float* w_hh_mid = (const float*)d_in[6];
  const float* b_ih_mid = (const float*)d_in[7];
  const float* b_hh_mid = (const float*)d_in[8];
  const float* fc_w     = (const float*)d_in[9];
  const float* fc_b     = (const float*)d_in[10];

  char* p = (char*)d_ws;
  auto take = [&](size_t n) { char* q = p; p += (n + 255) & ~(size_t)255; return q; };
  unsigned short* xb        = (unsigned short*)take((size_t)16384 * II * 2);
  unsigned short* wihin_hi  = (unsigned short*)take((size_t)N4H * II * 2);
  unsigned short* wihin_lo  = (unsigned short*)take((size_t)N4H * II * 2);
  unsigned short* whhin_hi  = (unsigned short*)take((size_t)N4H * HH * 2);
  unsigned short* whhin_lo  = (unsigned short*)take((size_t)N4H * HH * 2);
  unsigned short* wihmid_hi = (unsigned short*)take((size_t)N4H * HH * 2);
  unsigned short* wihmid_lo = (unsigned short*)take((size_t)N4H * HH * 2);
  unsigned short* whhmid_hi = (unsigned short*)take((size_t)N4H * HH * 2);
  unsigned short* whhmid_lo = (unsigned short*)take((size_t)N4H * HH * 2);
  unsigned short* fchi      = (unsigned short*)take((size_t)OO * 2 * HH * 2);
  unsigned short* fclo      = (unsigned short*)take((size_t)OO * 2 * HH * 2);
  float* bias0p             = (float*)take((size_t)N4H * 4);
  float* biasmp             = (float*)take((size_t)N4H * 4);
  float* g0x                = (float*)take((size_t)16384 * N4H * 4);  // also g1x-fwd
  float* g1xb               = (float*)take((size_t)16384 * N4H * 4);
  unsigned short* h0        = (unsigned short*)take((size_t)2 * TTHB * 2);
  unsigned short* out1      = (unsigned short*)take((size_t)2 * TTHB * 2);
  unsigned int* flags       = (unsigned int*)take(4096);

  float* y_out     = (float*)d_out;
  float* gates_out = y_out + (size_t)BB * TT * OO;
  float* hn_out    = gates_out + (size_t)TT * 4 * BB * 2 * HH;

  hipMemsetAsync(flags, 0, 4096, stream);

  prep_w<<<256, 256, 0, stream>>>(w_ih_in, wihin_hi, wihin_lo, II, N4H, 1);
  prep_w<<<512, 256, 0, stream>>>(w_hh_in, whhin_hi, whhin_lo, HH, N4H, 1);
  prep_w<<<512, 256, 0, stream>>>(w_ih_mid, wihmid_hi, wihmid_lo, HH, N4H, 1);
  prep_w<<<512, 256, 0, stream>>>(w_hh_mid, whhmid_hi, whhmid_lo, HH, N4H, 1);
  prep_w<<<128, 256, 0, stream>>>(fc_w, fchi, fclo, 2 * HH, OO, 0);
  prep_bias<<<8, 256, 0, stream>>>(b_ih_in, b_hh_in, b_ih_mid, b_hh_mid, bias0p, biasmp);
  prep_x<<<2048, 256, 0, stream>>>(inputs, xb);
  gemm_g0<<<8192, 256, 0, stream>>>(xb, wihin_hi, wihin_lo, bias0p, g0x);
  scan_l0<<<128, 256, 0, stream>>>(whhin_hi, whhin_lo, g0x, h0, flags);
  gemm_g1x<<<16384, 256, 0, stream>>>(h0, wihmid_hi, wihmid_lo, biasmp, g0x, g1xb);
  scan_l1<<<128, 256, 0, stream>>>(whhmid_hi, whhmid_lo, g0x, g1xb, out1,
                                   gates_out, hn_out, flags + 128);
  gemm_fc<<<1024, 256, 0, stream>>>(out1, fchi, fclo, fc_b, y_out);
}